// Round 8
// baseline (10914.780 us; speedup 1.0000x reference)
//
#include <hip/hip_runtime.h>
#include <math.h>

#define HIDDEN 512
#define EN 256
#define ET 512
#define VOCAB_N 300
#define VOCAB_T 10000
#define ATTN 50
#define V_OUT (VOCAB_T + ATTN + 3)   // 10053
#define EOF_N (VOCAB_N - 1)          // 299
#define EOF_T (VOCAB_T - 1)          // 9999
#define CONF 0.9f
#define SM_VAL (0.1f / (float)(V_OUT - 2))
#define BB 32
#define LL 128

#define GSG 8     // gates split-K (K=1280 -> 160/split, 5 chunks of 32)  [bit-exact]
#define GSL 6     // logits split-K (K=1536 -> 256/split, 8 chunks of 32) [bit-exact]
#define JBL 40    // logits j-blocks (40*256 >= 10053)
#define NLOG (JBL * GSL)   // 240 logits items
#define NGAT (32 * GSG)    // 256 gates items
#define NJIT 40            // per-thread j-iterations in score
#define LPN  (32 * JBL * GSL * 256)   // lpart floats per parity = 1,966,080

struct Params {
    const int   *n_t, *t_t, *p_t;
    const float *embN, *embT, *w_ih, *w_hh, *b_ih, *b_hh;
    const float *Wh_w, *Wh_b, *v_w, *v_b, *Wg_w, *Wg_b, *Ws_w, *Ws_b;
    float *out;
    float *hs, *c, *xbuf, *xg, *a_out, *s_t, *tl_partial, *gpart, *lpart;
    unsigned *flags;   // 32 flags, 16-uint (64B) padded; big path only
};

// ---------------- init: zero hs,c; xg = [embN[SOS] | embT[SOS] | h=0] ----------
__global__ void k_init(Params p) {
    int i = blockIdx.x * 256 + threadIdx.x;
    int stride = gridDim.x * 256;
    for (int k = i; k < BB * LL * 512; k += stride) p.hs[k] = 0.0f;
    for (int k = i; k < BB * 512; k += stride) p.c[k] = 0.0f;
    for (int k = i; k < BB * 1280; k += stride) {
        int kk = k % 1280;
        float v;
        if (kk < 256)      v = p.embN[kk];
        else if (kk < 768) v = p.embT[kk - 256];
        else               v = 0.0f;
        p.xg[k] = v;
    }
}

// -------- gates GEMM item: gpart[b][s][2048]; s==0 folds b_ih+b_hh -------------
static __device__ __forceinline__ void ph_gates(const Params& p, float* sm, int jb, int s) {
    float (*Ws)[64] = (float(*)[64])sm;            // [k][j^swz]  32*64
    float (*Xs)[32] = (float(*)[32])(sm + 2048);   // [k][b^swz]  32*32
    const float* __restrict__ w_ih = p.w_ih;
    const float* __restrict__ w_hh = p.w_hh;
    const float* __restrict__ xg   = p.xg;
    int jt = jb * 64;
    int tid = threadIdx.x;
    int jq = tid & 15;
    int bq = tid >> 4;
    int rowl = tid >> 3;          // 0..31
    int colq = tid & 7;           // k-col group
    int swz  = colq << 2;
    float4 wreg[2], xreg;
    float acc[2][4] = {{0.f,0.f,0.f,0.f},{0.f,0.f,0.f,0.f}};
    const int kbase = s * 160;
    {   // prefetch chunk 0 (coalesced)
        int kg = kbase + colq * 4;
        #pragma unroll
        for (int r = 0; r < 2; ++r) {
            int row = jt + r * 32 + rowl;
            wreg[r] = (kg < 768) ? *(const float4*)(w_ih + (size_t)row * 768 + kg)
                                 : *(const float4*)(w_hh + (size_t)row * 512 + (kg - 768));
        }
        xreg = *(const float4*)(xg + rowl * 1280 + kbase + colq * 4);
    }
    for (int ch = 0; ch < 5; ++ch) {
        __syncthreads();
        #pragma unroll
        for (int r = 0; r < 2; ++r) {
            int jp = (r * 32 + rowl) ^ swz;
            Ws[colq*4+0][jp] = wreg[r].x;
            Ws[colq*4+1][jp] = wreg[r].y;
            Ws[colq*4+2][jp] = wreg[r].z;
            Ws[colq*4+3][jp] = wreg[r].w;
        }
        int bp = rowl ^ swz;
        Xs[colq*4+0][bp] = xreg.x; Xs[colq*4+1][bp] = xreg.y;
        Xs[colq*4+2][bp] = xreg.z; Xs[colq*4+3][bp] = xreg.w;
        __syncthreads();
        if (ch < 4) {
            int k0 = kbase + (ch + 1) * 32;
            int kg = k0 + colq * 4;
            #pragma unroll
            for (int r = 0; r < 2; ++r) {
                int row = jt + r * 32 + rowl;
                wreg[r] = (kg < 768) ? *(const float4*)(w_ih + (size_t)row * 768 + kg)
                                     : *(const float4*)(w_hh + (size_t)row * 512 + (kg - 768));
            }
            xreg = *(const float4*)(xg + rowl * 1280 + k0 + colq * 4);
        }
        #pragma unroll 4
        for (int kk = 0; kk < 32; ++kk) {
            int xk2 = ((kk >> 2) & 7) << 2;
            float4 w = *(const float4*)&Ws[kk][(jq * 4) ^ xk2];
            float2 x = *(const float2*)&Xs[kk][(bq * 2) ^ xk2];
            acc[0][0] += x.x*w.x; acc[0][1] += x.x*w.y; acc[0][2] += x.x*w.z; acc[0][3] += x.x*w.w;
            acc[1][0] += x.y*w.x; acc[1][1] += x.y*w.y; acc[1][2] += x.y*w.z; acc[1][3] += x.y*w.w;
        }
    }
    float4 bsum = make_float4(0.f, 0.f, 0.f, 0.f);
    if (s == 0) {
        float4 bi = *(const float4*)(p.b_ih + jt + jq * 4);
        float4 bh = *(const float4*)(p.b_hh + jt + jq * 4);
        bsum = make_float4(bi.x + bh.x, bi.y + bh.y, bi.z + bh.z, bi.w + bh.w);
    }
    #pragma unroll
    for (int r = 0; r < 2; ++r) {
        float4 v = make_float4(acc[r][0] + bsum.x, acc[r][1] + bsum.y,
                               acc[r][2] + bsum.z, acc[r][3] + bsum.w);
        *(float4*)(p.gpart + (((size_t)(bq * 2 + r)) * GSG + s) * 2048 + jt + jq * 4) = v;
    }
}

// ------ logits GEMM item -> lpart[par][b][jb][s][256]; s==0 folds Wg_b ---------
static __device__ __forceinline__ void ph_logits(const Params& p, float* sm, int lb, int par) {
    float (*Ws)[256] = (float(*)[256])sm;              // [k][j^swz]  32*256
    float (*Xs)[32]  = (float(*)[32])(sm + 32 * 256);  // [k][b^swz]  32*32
    const float* __restrict__ Wg_w = p.Wg_w;
    const float* __restrict__ Wg_b = p.Wg_b;
    const float* __restrict__ xbuf = p.xbuf;
    int tid = threadIdx.x;
    int jb = lb % JBL, s = lb / JBL;
    int jt = jb * 256;
    int jq = tid & 31;
    int bq = tid >> 5;
    int rowl = tid >> 3;
    int colq = tid & 7;
    int swz  = colq << 2;
    float4 wreg[8], xreg;
    float acc[4][8];
    #pragma unroll
    for (int r = 0; r < 4; ++r)
        #pragma unroll
        for (int q = 0; q < 8; ++q) acc[r][q] = 0.f;
    const int kbase = s * 256;
    {   // prefetch chunk 0
        int kg = kbase + colq * 4;
        #pragma unroll
        for (int r = 0; r < 8; ++r) {
            int grow = jt + r * 32 + rowl;
            if (grow >= V_OUT) grow = 0;
            wreg[r] = *(const float4*)(Wg_w + (size_t)grow * 1536 + kg);
        }
        xreg = *(const float4*)(xbuf + rowl * 1536 + kbase + colq * 4);
    }
    for (int ch = 0; ch < 8; ++ch) {
        __syncthreads();
        #pragma unroll
        for (int r = 0; r < 8; ++r) {
            int jp = (r * 32 + rowl) ^ swz;
            Ws[colq*4+0][jp] = wreg[r].x;
            Ws[colq*4+1][jp] = wreg[r].y;
            Ws[colq*4+2][jp] = wreg[r].z;
            Ws[colq*4+3][jp] = wreg[r].w;
        }
        int bp = rowl ^ swz;
        Xs[colq*4+0][bp] = xreg.x; Xs[colq*4+1][bp] = xreg.y;
        Xs[colq*4+2][bp] = xreg.z; Xs[colq*4+3][bp] = xreg.w;
        __syncthreads();
        if (ch < 7) {
            int k0 = kbase + (ch + 1) * 32;
            int kg = k0 + colq * 4;
            #pragma unroll
            for (int r = 0; r < 8; ++r) {
                int grow = jt + r * 32 + rowl;
                if (grow >= V_OUT) grow = 0;
                wreg[r] = *(const float4*)(Wg_w + (size_t)grow * 1536 + kg);
            }
            xreg = *(const float4*)(xbuf + rowl * 1536 + k0 + colq * 4);
        }
        #pragma unroll 4
        for (int kk = 0; kk < 32; ++kk) {
            int xk2 = ((kk >> 2) & 7) << 2;
            float4 xv = *(const float4*)&Xs[kk][(bq * 4) ^ xk2];
            float4 w0 = *(const float4*)&Ws[kk][(jq * 4) ^ xk2];
            float4 w1 = *(const float4*)&Ws[kk][128 + ((jq * 4) ^ xk2)];
            acc[0][0] += xv.x*w0.x; acc[0][1] += xv.x*w0.y; acc[0][2] += xv.x*w0.z; acc[0][3] += xv.x*w0.w;
            acc[0][4] += xv.x*w1.x; acc[0][5] += xv.x*w1.y; acc[0][6] += xv.x*w1.z; acc[0][7] += xv.x*w1.w;
            acc[1][0] += xv.y*w0.x; acc[1][1] += xv.y*w0.y; acc[1][2] += xv.y*w0.z; acc[1][3] += xv.y*w0.w;
            acc[1][4] += xv.y*w1.x; acc[1][5] += xv.y*w1.y; acc[1][6] += xv.y*w1.z; acc[1][7] += xv.y*w1.w;
            acc[2][0] += xv.z*w0.x; acc[2][1] += xv.z*w0.y; acc[2][2] += xv.z*w0.z; acc[2][3] += xv.z*w0.w;
            acc[2][4] += xv.z*w1.x; acc[2][5] += xv.z*w1.y; acc[2][6] += xv.z*w1.z; acc[2][7] += xv.z*w1.w;
            acc[3][0] += xv.w*w0.x; acc[3][1] += xv.w*w0.y; acc[3][2] += xv.w*w0.z; acc[3][3] += xv.w*w0.w;
            acc[3][4] += xv.w*w1.x; acc[3][5] += xv.w*w1.y; acc[3][6] += xv.w*w1.z; acc[3][7] += xv.w*w1.w;
        }
    }
    float* lpp = p.lpart + (size_t)par * LPN;
    #pragma unroll
    for (int r = 0; r < 4; ++r) {
        int bb2 = bq * 4 + r;
        float* dst = lpp + (((size_t)bb2 * JBL + jb) * GSL + s) * 256;
        #pragma unroll
        for (int q = 0; q < 4; ++q) {
            int c1 = jq * 4 + q;
            float v1 = acc[r][q];
            if (s == 0) { int j1 = jt + c1; v1 += (j1 < V_OUT ? Wg_b[j1] : 0.0f); }
            dst[c1] = v1;
            int c2 = 128 + jq * 4 + q;
            float v2 = acc[r][4 + q];
            if (s == 0) { int j2 = jt + c2; v2 += (j2 < V_OUT ? Wg_b[j2] : 0.0f); }
            dst[c2] = v2;
        }
    }
}

// ----- cell item + folded Wh (bit-exact; a_out/s_t parity-buffered by it&1) -----
static __device__ __forceinline__ void ph_cell(const Params& p, float* sm, int b, int it) {
    float* h_s = sm;          // 512
    float* c_s = sm + 512;    // 512
    float* red = sm + 1024;   // 256
    int tid = threadIdx.x;
    int parent = (it == 0) ? 0 : p.p_t[b * LL + it - 1];
    for (int k = tid; k < 512; k += 256)
        p.xbuf[b * 1536 + 1024 + k] = p.hs[((size_t)b * LL + parent) * 512 + k];
    const float* __restrict__ gp = p.gpart + (size_t)b * (GSG * 2048);
    for (int jj = tid; jj < 512; jj += 256) {
        float ig = gp[jj];
        float fg = gp[512 + jj];
        float gg = gp[1024 + jj];
        float og = gp[1536 + jj];
        #pragma unroll
        for (int s = 1; s < GSG; ++s) {
            const float* gps = gp + s * 2048;
            ig += gps[jj]; fg += gps[512 + jj]; gg += gps[1024 + jj]; og += gps[1536 + jj];
        }
        float si = 1.0f / (1.0f + expf(-ig));
        float sf = 1.0f / (1.0f + expf(-fg));
        float so = 1.0f / (1.0f + expf(-og));
        float cn = sf * p.c[b * 512 + jj] + si * tanhf(gg);
        float hn = so * tanhf(cn);
        c_s[jj] = cn; h_s[jj] = hn;
        p.c[b * 512 + jj] = cn;
    }
    __syncthreads();
    int nn = p.n_t[b * LL + it], tn = p.t_t[b * LL + it];
    for (int k = tid; k < 512; k += 256) {
        float hv = h_s[k], cv = c_s[k];
        p.hs[((size_t)b * LL + it) * 512 + k] = hv;
        p.xbuf[b * 1536 + k] = hv;
        p.xbuf[b * 1536 + 512 + k] = cv;
        p.xg[b * 1280 + 768 + k] = hv;
        p.xg[b * 1280 + 256 + k] = p.embT[(size_t)tn * 512 + k];
    }
    p.xg[b * 1280 + tid] = p.embN[(size_t)nn * 256 + tid];
    // s_t
    float acc = 0.0f;
    for (int k = tid; k < 512; k += 256) acc += h_s[k] * p.Ws_w[k];
    for (int k = tid; k < 512; k += 256) acc += c_s[k] * p.Ws_w[512 + k];
    red[tid] = acc;
    __syncthreads();
    for (int s2 = 128; s2 > 0; s2 >>= 1) {
        if (tid < s2) red[tid] += red[tid + s2];
        __syncthreads();
    }
    if (tid == 0)
        p.s_t[(it & 1) * BB + b] = 1.0f / (1.0f + expf(-(red[0] + p.Ws_b[0])));
    // folded Wh GEMM (identical per-(b,j) k-order; bias last; parity buf)
    float* ao = p.a_out + (size_t)(it & 1) * (BB * 512) + b * 512;
    for (int j = tid; j < 512; j += 256) {
        const float* wr = p.Wh_w + (size_t)j * 512;
        float a0 = 0.f;
        #pragma unroll 4
        for (int k = 0; k < 512; k += 4) {
            float4 w = *(const float4*)(wr + k);
            float4 x = *(const float4*)(h_s + k);
            a0 += w.x*x.x + w.y*x.y + w.z*x.z + w.w*x.w;
        }
        ao[j] = a0 + p.Wh_b[j];
    }
}

// ------- scorefinal for step itm (a_out parity; lpart parity) -------------------
static __device__ __forceinline__ void ph_score(const Params& p, float* sm, int b, int itm, int par) {
    float* a_s  = sm;                 // 512
    float* vw_s = sm + 512;           // 512
    float* sc   = sm + 1024;          // 52 (pad 64)
    float* mv   = sm + 1088;          // 256
    int*   mi   = (int*)(sm + 1344);  // 256
    float* sv   = sm + 1600;          // 256
    float* sh   = sm + 1856;          // 2: vt, ve
    int tid = threadIdx.x;
    int lane = tid & 63, wv = tid >> 6;
    const float* ao = p.a_out + (size_t)(itm & 1) * (BB * 512) + b * 512;
    for (int k = tid; k < 512; k += 256) {
        a_s[k]  = ao[k];
        vw_s[k] = p.v_w[k];
    }
    __syncthreads();
    float vb0 = p.v_b[0];
    for (int w = wv; w < ATTN; w += 4) {
        int idx = itm + w - ATTN;
        int idxc = idx < 0 ? 0 : idx;
        bool mask = (idx < 0) || (p.n_t[b * LL + idxc] == EOF_N);
        const float* mrow = p.hs + ((size_t)b * LL + idxc) * 512;
        float acc = 0.0f;
        #pragma unroll
        for (int kk = 0; kk < 8; ++kk) {
            int k = lane + kk * 64;
            float x = a_s[k] + mrow[k];
            float e = __expf(2.0f * x);
            acc += vw_s[k] * (1.0f - 2.0f / (e + 1.0f));
        }
        for (int o = 32; o > 0; o >>= 1) acc += __shfl_down(acc, o);
        if (lane == 0) sc[w] = mask ? -1e20f : (acc + vb0);
    }
    __syncthreads();
    if (tid == 0) {
        float m = -INFINITY;
        for (int w = 0; w < ATTN; w++) m = fmaxf(m, sc[w]);
        float Z = 0.0f, emax = 0.0f;
        for (int w = 0; w < ATTN; w++) {
            float e = __expf(sc[w] - m);
            Z += e;
            if (e > emax) emax = e;
        }
        sc[50] = emax / Z;
        sc[51] = 1.0f;
    }
    int t_col = p.t_t[b * LL + itm];
    float lmax = -INFINITY; int limax = 0; float lsum = 0.0f;
    float vvr[NJIT];
    const float* __restrict__ lpb = p.lpart + (size_t)par * LPN + (size_t)b * (JBL * GSL * 256) + tid;
    #pragma unroll
    for (int i = 0; i < NJIT; ++i) {
        const float* base = lpb + i * (GSL * 256);
        float v = base[0];
        v += base[256];
        v += base[512];
        v += base[768];
        v += base[1024];
        v += base[1280];
        int j = i * 256 + tid;
        if (j < V_OUT) {
            vvr[i] = v;
            lsum += v;
            if (v > lmax) { lmax = v; limax = j; }
            if (j == t_col) sh[0] = v;
            if (j == EOF_T) sh[1] = v;
        }
    }
    mv[tid] = lmax; mi[tid] = limax; sv[tid] = lsum;
    __syncthreads();
    for (int s2 = 128; s2 > 0; s2 >>= 1) {
        if (tid < s2) {
            if (mv[tid + s2] > mv[tid] || (mv[tid + s2] == mv[tid] && mi[tid + s2] < mi[tid])) {
                mv[tid] = mv[tid + s2]; mi[tid] = mi[tid + s2];
            }
            sv[tid] += sv[tid + s2];
        }
        __syncthreads();
    }
    float M = mv[0]; int argJ = mi[0]; float sumL = sv[0];
    __syncthreads();
    float esum = 0.0f;
    #pragma unroll
    for (int i = 0; i < NJIT; ++i) {
        int j = i * 256 + tid;
        if (j < V_OUT) esum += expf(vvr[i] - M);
    }
    sv[tid] = esum;
    __syncthreads();
    for (int s2 = 128; s2 > 0; s2 >>= 1) {
        if (tid < s2) sv[tid] += sv[tid + s2];
        __syncthreads();
    }
    if (tid == 0) {
        float lse = logf(sv[0]);
        float st = p.s_t[(itm & 1) * BB + b];
        float amax = sc[50], asum = sc[51];
        float max_out = st * (-lse);
        float max_loc = (1.0f - st) * amax;
        bool cond = max_out > max_loc;
        const float CONST_T = CONF * logf(CONF) + 0.1f * logf(SM_VAL);
        float tl; int topi;
        if (!cond) {
            topi = argJ;
            float off = M + lse;
            float out_t = st * (sh[0] - off);
            float out_e = st * (sh[1] - off);
            float S = st * (sumL - (float)V_OUT * off);
            tl = CONST_T - (SM_VAL * (S - out_e - out_t) + CONF * out_t);
        } else {
            topi = 0;
            float S = (1.0f - st) * asum;
            tl = CONST_T - SM_VAL * S;
        }
        if (t_col == EOF_T) tl = 0.0f;
        p.tl_partial[itm * BB + b] = tl;
        p.out[1 + b * LL + itm] = (float)topi;
    }
}

// ---------------- kernels --------------------------------------------------------
// pre: gates(0) only
__global__ __launch_bounds__(256) void k_pre(Params p) {
    __shared__ __align__(16) float sm[9216];
    ph_gates(p, sm, blockIdx.x & 31, blockIdx.x >> 5);
}

// FUSED per-step kernel (big-ws path):
//   bx 0..31   : cell(it) -> release flag[b]=it+1
//   bx 32..63  : score(it-1)   [no wait: inputs from previous kernels]
//   bx 64..303 : wait flags -> logits(it), parity it&1
//   bx 304..431: wait flags -> gates(it+1), 2 items/block
__global__ __launch_bounds__(256) void k_step(Params p, int it, int with_gates) {
    __shared__ __align__(16) float sm[9216];
    int bx = blockIdx.x, tid = threadIdx.x;
    if (bx < 32) {
        ph_cell(p, sm, bx, it);
        __syncthreads();   // all block stores complete before flag release
        if (tid == 0)
            __hip_atomic_store(&p.flags[bx * 16], (unsigned)(it + 1),
                               __ATOMIC_RELEASE, __HIP_MEMORY_SCOPE_AGENT);
        return;
    }
    if (bx < 64) {
        if (it > 0) ph_score(p, sm, bx - 32, it - 1, (it - 1) & 1);
        return;
    }
    if (bx >= 304 && !with_gates) return;
    // ---- wait for all 32 cell flags (one-directional; blocks all co-resident) ----
    if (tid == 0) {
        unsigned target = (unsigned)(it + 1);
        for (int b2 = 0; b2 < 32; ++b2) {
            while (__hip_atomic_load(&p.flags[b2 * 16], __ATOMIC_RELAXED,
                                     __HIP_MEMORY_SCOPE_AGENT) < target)
                __builtin_amdgcn_s_sleep(1);
        }
        __threadfence();   // device-scope acquire after observing all releases
    }
    __syncthreads();
    if (bx < 304) {
        ph_logits(p, sm, bx - 64, it & 1);
    } else {
        int g = bx - 304;                    // 2 gates items per block
        int g1 = 2 * g, g2 = 2 * g + 1;
        ph_gates(p, sm, g1 & 31, g1 >> 5);
        ph_gates(p, sm, g2 & 31, g2 >> 5);
    }
}

// small-ws fallback (R6-proven 2-kernel structure, single lpart parity 0)
__global__ __launch_bounds__(256) void k_phA(Params p, int it) {
    __shared__ __align__(16) float sm[9216];
    int bx = blockIdx.x;
    if (bx < 32) ph_cell(p, sm, bx, it);
    else if (it > 0) ph_score(p, sm, bx - 32, it - 1, 0);
}
__global__ __launch_bounds__(256) void k_phB(Params p, int with_gates) {
    __shared__ __align__(16) float sm[9216];
    int bx = blockIdx.x;
    if (bx < NLOG) ph_logits(p, sm, bx, 0);
    else if (with_gates) {
        int g = bx - NLOG;
        int g1 = 2 * g, g2 = 2 * g + 1;
        ph_gates(p, sm, g1 & 31, g1 >> 5);
        ph_gates(p, sm, g2 & 31, g2 >> 5);
    }
}

// final score(127)
__global__ __launch_bounds__(256) void k_final(Params p, int par) {
    __shared__ __align__(16) float sm[9216];
    ph_score(p, sm, blockIdx.x, LL - 1, par);
}

__global__ void k_sumloss(Params p) {
    __shared__ float r[256];
    float a = 0.0f;
    for (int i = threadIdx.x; i < BB * LL; i += 256) a += p.tl_partial[i];
    r[threadIdx.x] = a;
    __syncthreads();
    for (int s = 128; s > 0; s >>= 1) {
        if (threadIdx.x < s) r[threadIdx.x] += r[threadIdx.x + s];
        __syncthreads();
    }
    if (threadIdx.x == 0) p.out[0] = r[0];
}

extern "C" void kernel_launch(void* const* d_in, const int* in_sizes, int n_in,
                              void* d_out, int out_size, void* d_ws, size_t ws_size,
                              hipStream_t stream) {
    (void)in_sizes; (void)n_in; (void)out_size;
    Params p;
    p.n_t  = (const int*)d_in[0];
    p.t_t  = (const int*)d_in[1];
    p.p_t  = (const int*)d_in[2];
    p.embN = (const float*)d_in[3];
    p.embT = (const float*)d_in[4];
    p.w_ih = (const float*)d_in[5];
    p.w_hh = (const float*)d_in[6];
    p.b_ih = (const float*)d_in[7];
    p.b_hh = (const float*)d_in[8];
    p.Wh_w = (const float*)d_in[9];
    p.Wh_b = (const float*)d_in[10];
    p.v_w  = (const float*)d_in[11];
    p.v_b  = (const float*)d_in[12];
    p.Wg_w = (const float*)d_in[13];
    p.Wg_b = (const float*)d_in[14];
    p.Ws_w = (const float*)d_in[15];
    p.Ws_b = (const float*)d_in[16];
    p.out  = (float*)d_out;

    // workspace layout (floats)
    float* ws = (float*)d_ws;
    p.hs         = ws;                       // 2,097,152
    p.c          = p.hs + 2097152;           // 16,384
    p.xbuf       = p.c + 16384;              // 49,152  [h|c|hcp]
    p.xg         = p.xbuf + 49152;           // 40,960  [embN|embT|h]
    p.a_out      = p.xg + 40960;             // 32,768  (parity)
    p.s_t        = p.a_out + 32768;          // 64      (parity)
    p.tl_partial = p.s_t + 64;               // 4,096
    p.gpart      = p.tl_partial + 4096;      // 524,288  [b][s][j]
    p.lpart      = p.gpart + 524288;         // LPN (small) or 2*LPN (big)
    // big path adds 2nd lpart parity + flags
    const size_t base_f = 2097152 + 16384 + 49152 + 40960 + 32768 + 64 + 4096 + 524288;
    const size_t req_big = (base_f + 2 * (size_t)LPN + 512) * 4;
    bool big = (ws_size >= req_big);
    p.flags = (unsigned*)(p.lpart + (big ? 2 * (size_t)LPN : (size_t)LPN));

    if (big) (void)hipMemsetAsync((void*)p.flags, 0, 32 * 16 * 4, stream);
    k_init<<<2048, 256, 0, stream>>>(p);
    k_pre<<<NGAT, 256, 0, stream>>>(p);                       // gates(0)
    if (big) {
        for (int it = 0; it < LL; ++it) {
            int wg = (it < LL - 1) ? 1 : 0;
            k_step<<<wg ? 432 : 304, 256, 0, stream>>>(p, it, wg);
        }
        k_final<<<32, 256, 0, stream>>>(p, (LL - 1) & 1);     // parity 1
    } else {
        for (int it = 0; it < LL; ++it) {
            k_phA<<<64, 256, 0, stream>>>(p, it);
            int wg = (it < LL - 1) ? 1 : 0;
            k_phB<<<wg ? (NLOG + 128) : NLOG, 256, 0, stream>>>(p, wg);
        }
        k_final<<<32, 256, 0, stream>>>(p, 0);
    }
    k_sumloss<<<1, 256, 0, stream>>>(p);
}

// Round 9
// 6793.252 us; speedup vs baseline: 1.6067x; 1.6067x over previous
//
#include <hip/hip_runtime.h>
#include <math.h>

#define HIDDEN 512
#define EN 256
#define ET 512
#define VOCAB_N 300
#define VOCAB_T 10000
#define ATTN 50
#define V_OUT (VOCAB_T + ATTN + 3)   // 10053
#define EOF_N (VOCAB_N - 1)          // 299
#define EOF_T (VOCAB_T - 1)          // 9999
#define CONF 0.9f
#define SM_VAL (0.1f / (float)(V_OUT - 2))
#define BB 32
#define LL 128

#define GSG 8     // gates split-K (K=1280 -> 160/split, 5 chunks of 32)  [bit-exact]
#define GSL 6     // logits split-K (K=1536 -> 256/split, 8 chunks of 32) [bit-exact]
#define JBL 40    // logits j-blocks (40*256 >= 10053)
#define NLOG (JBL * GSL)   // 240 logits items
#define NGAT (32 * GSG)    // 256 gates items
#define NJIT 40            // per-thread j-iterations in score
#define LPN  (32 * JBL * GSL * 256)   // lpart floats per parity = 1,966,080

struct Params {
    const int   *n_t, *t_t, *p_t;
    const float *embN, *embT, *w_ih, *w_hh, *b_ih, *b_hh;
    const float *Wh_w, *Wh_b, *v_w, *v_b, *Wg_w, *Wg_b, *Ws_w, *Ws_b;
    float *out;
    float *hs, *c, *xbuf, *xg, *a_out, *s_t, *tl_partial, *gpart, *lpart;
};

// ---------------- init: zero hs,c; xg = [embN[SOS] | embT[SOS] | h=0] ----------
__global__ void k_init(Params p) {
    int i = blockIdx.x * 256 + threadIdx.x;
    int stride = gridDim.x * 256;
    for (int k = i; k < BB * LL * 512; k += stride) p.hs[k] = 0.0f;
    for (int k = i; k < BB * 512; k += stride) p.c[k] = 0.0f;
    for (int k = i; k < BB * 1280; k += stride) {
        int kk = k % 1280;
        float v;
        if (kk < 256)      v = p.embN[kk];
        else if (kk < 768) v = p.embT[kk - 256];
        else               v = 0.0f;
        p.xg[k] = v;
    }
}

// -------- gates GEMM item: gpart[b][s][2048]; s==0 folds b_ih+b_hh -------------
static __device__ __forceinline__ void ph_gates(const Params& p, float* sm, int jb, int s) {
    float (*Ws)[64] = (float(*)[64])sm;            // [k][j^swz]  32*64
    float (*Xs)[32] = (float(*)[32])(sm + 2048);   // [k][b^swz]  32*32
    const float* __restrict__ w_ih = p.w_ih;
    const float* __restrict__ w_hh = p.w_hh;
    const float* __restrict__ xg   = p.xg;
    int jt = jb * 64;
    int tid = threadIdx.x;
    int jq = tid & 15;
    int bq = tid >> 4;
    int rowl = tid >> 3;          // 0..31
    int colq = tid & 7;           // k-col group
    int swz  = colq << 2;
    float4 wreg[2], xreg;
    float acc[2][4] = {{0.f,0.f,0.f,0.f},{0.f,0.f,0.f,0.f}};
    const int kbase = s * 160;
    {   // prefetch chunk 0 (coalesced)
        int kg = kbase + colq * 4;
        #pragma unroll
        for (int r = 0; r < 2; ++r) {
            int row = jt + r * 32 + rowl;
            wreg[r] = (kg < 768) ? *(const float4*)(w_ih + (size_t)row * 768 + kg)
                                 : *(const float4*)(w_hh + (size_t)row * 512 + (kg - 768));
        }
        xreg = *(const float4*)(xg + rowl * 1280 + kbase + colq * 4);
    }
    for (int ch = 0; ch < 5; ++ch) {
        __syncthreads();
        #pragma unroll
        for (int r = 0; r < 2; ++r) {
            int jp = (r * 32 + rowl) ^ swz;
            Ws[colq*4+0][jp] = wreg[r].x;
            Ws[colq*4+1][jp] = wreg[r].y;
            Ws[colq*4+2][jp] = wreg[r].z;
            Ws[colq*4+3][jp] = wreg[r].w;
        }
        int bp = rowl ^ swz;
        Xs[colq*4+0][bp] = xreg.x; Xs[colq*4+1][bp] = xreg.y;
        Xs[colq*4+2][bp] = xreg.z; Xs[colq*4+3][bp] = xreg.w;
        __syncthreads();
        if (ch < 4) {
            int k0 = kbase + (ch + 1) * 32;
            int kg = k0 + colq * 4;
            #pragma unroll
            for (int r = 0; r < 2; ++r) {
                int row = jt + r * 32 + rowl;
                wreg[r] = (kg < 768) ? *(const float4*)(w_ih + (size_t)row * 768 + kg)
                                     : *(const float4*)(w_hh + (size_t)row * 512 + (kg - 768));
            }
            xreg = *(const float4*)(xg + rowl * 1280 + k0 + colq * 4);
        }
        #pragma unroll 4
        for (int kk = 0; kk < 32; ++kk) {
            int xk2 = ((kk >> 2) & 7) << 2;
            float4 w = *(const float4*)&Ws[kk][(jq * 4) ^ xk2];
            float2 x = *(const float2*)&Xs[kk][(bq * 2) ^ xk2];
            acc[0][0] += x.x*w.x; acc[0][1] += x.x*w.y; acc[0][2] += x.x*w.z; acc[0][3] += x.x*w.w;
            acc[1][0] += x.y*w.x; acc[1][1] += x.y*w.y; acc[1][2] += x.y*w.z; acc[1][3] += x.y*w.w;
        }
    }
    float4 bsum = make_float4(0.f, 0.f, 0.f, 0.f);
    if (s == 0) {
        float4 bi = *(const float4*)(p.b_ih + jt + jq * 4);
        float4 bh = *(const float4*)(p.b_hh + jt + jq * 4);
        bsum = make_float4(bi.x + bh.x, bi.y + bh.y, bi.z + bh.z, bi.w + bh.w);
    }
    #pragma unroll
    for (int r = 0; r < 2; ++r) {
        float4 v = make_float4(acc[r][0] + bsum.x, acc[r][1] + bsum.y,
                               acc[r][2] + bsum.z, acc[r][3] + bsum.w);
        *(float4*)(p.gpart + (((size_t)(bq * 2 + r)) * GSG + s) * 2048 + jt + jq * 4) = v;
    }
}

// ------ logits GEMM item -> lpart[par][b][jb][s][256]; s==0 folds Wg_b ---------
static __device__ __forceinline__ void ph_logits(const Params& p, float* sm, int lb, int par) {
    float (*Ws)[256] = (float(*)[256])sm;              // [k][j^swz]  32*256
    float (*Xs)[32]  = (float(*)[32])(sm + 32 * 256);  // [k][b^swz]  32*32
    const float* __restrict__ Wg_w = p.Wg_w;
    const float* __restrict__ Wg_b = p.Wg_b;
    const float* __restrict__ xbuf = p.xbuf;
    int tid = threadIdx.x;
    int jb = lb % JBL, s = lb / JBL;
    int jt = jb * 256;
    int jq = tid & 31;
    int bq = tid >> 5;
    int rowl = tid >> 3;
    int colq = tid & 7;
    int swz  = colq << 2;
    float4 wreg[8], xreg;
    float acc[4][8];
    #pragma unroll
    for (int r = 0; r < 4; ++r)
        #pragma unroll
        for (int q = 0; q < 8; ++q) acc[r][q] = 0.f;
    const int kbase = s * 256;
    {   // prefetch chunk 0
        int kg = kbase + colq * 4;
        #pragma unroll
        for (int r = 0; r < 8; ++r) {
            int grow = jt + r * 32 + rowl;
            if (grow >= V_OUT) grow = 0;
            wreg[r] = *(const float4*)(Wg_w + (size_t)grow * 1536 + kg);
        }
        xreg = *(const float4*)(xbuf + rowl * 1536 + kbase + colq * 4);
    }
    for (int ch = 0; ch < 8; ++ch) {
        __syncthreads();
        #pragma unroll
        for (int r = 0; r < 8; ++r) {
            int jp = (r * 32 + rowl) ^ swz;
            Ws[colq*4+0][jp] = wreg[r].x;
            Ws[colq*4+1][jp] = wreg[r].y;
            Ws[colq*4+2][jp] = wreg[r].z;
            Ws[colq*4+3][jp] = wreg[r].w;
        }
        int bp = rowl ^ swz;
        Xs[colq*4+0][bp] = xreg.x; Xs[colq*4+1][bp] = xreg.y;
        Xs[colq*4+2][bp] = xreg.z; Xs[colq*4+3][bp] = xreg.w;
        __syncthreads();
        if (ch < 7) {
            int k0 = kbase + (ch + 1) * 32;
            int kg = k0 + colq * 4;
            #pragma unroll
            for (int r = 0; r < 8; ++r) {
                int grow = jt + r * 32 + rowl;
                if (grow >= V_OUT) grow = 0;
                wreg[r] = *(const float4*)(Wg_w + (size_t)grow * 1536 + kg);
            }
            xreg = *(const float4*)(xbuf + rowl * 1536 + k0 + colq * 4);
        }
        #pragma unroll 4
        for (int kk = 0; kk < 32; ++kk) {
            int xk2 = ((kk >> 2) & 7) << 2;
            float4 xv = *(const float4*)&Xs[kk][(bq * 4) ^ xk2];
            float4 w0 = *(const float4*)&Ws[kk][(jq * 4) ^ xk2];
            float4 w1 = *(const float4*)&Ws[kk][128 + ((jq * 4) ^ xk2)];
            acc[0][0] += xv.x*w0.x; acc[0][1] += xv.x*w0.y; acc[0][2] += xv.x*w0.z; acc[0][3] += xv.x*w0.w;
            acc[0][4] += xv.x*w1.x; acc[0][5] += xv.x*w1.y; acc[0][6] += xv.x*w1.z; acc[0][7] += xv.x*w1.w;
            acc[1][0] += xv.y*w0.x; acc[1][1] += xv.y*w0.y; acc[1][2] += xv.y*w0.z; acc[1][3] += xv.y*w0.w;
            acc[1][4] += xv.y*w1.x; acc[1][5] += xv.y*w1.y; acc[1][6] += xv.y*w1.z; acc[1][7] += xv.y*w1.w;
            acc[2][0] += xv.z*w0.x; acc[2][1] += xv.z*w0.y; acc[2][2] += xv.z*w0.z; acc[2][3] += xv.z*w0.w;
            acc[2][4] += xv.z*w1.x; acc[2][5] += xv.z*w1.y; acc[2][6] += xv.z*w1.z; acc[2][7] += xv.z*w1.w;
            acc[3][0] += xv.w*w0.x; acc[3][1] += xv.w*w0.y; acc[3][2] += xv.w*w0.z; acc[3][3] += xv.w*w0.w;
            acc[3][4] += xv.w*w1.x; acc[3][5] += xv.w*w1.y; acc[3][6] += xv.w*w1.z; acc[3][7] += xv.w*w1.w;
        }
    }
    float* lpp = p.lpart + (size_t)par * LPN;
    #pragma unroll
    for (int r = 0; r < 4; ++r) {
        int bb2 = bq * 4 + r;
        float* dst = lpp + (((size_t)bb2 * JBL + jb) * GSL + s) * 256;
        #pragma unroll
        for (int q = 0; q < 4; ++q) {
            int c1 = jq * 4 + q;
            float v1 = acc[r][q];
            if (s == 0) { int j1 = jt + c1; v1 += (j1 < V_OUT ? Wg_b[j1] : 0.0f); }
            dst[c1] = v1;
            int c2 = 128 + jq * 4 + q;
            float v2 = acc[r][4 + q];
            if (s == 0) { int j2 = jt + c2; v2 += (j2 < V_OUT ? Wg_b[j2] : 0.0f); }
            dst[c2] = v2;
        }
    }
}

// ---------------- Wh item: one block per b; a_out parity by it&1 ----------------
static __device__ __forceinline__ void ph_wh(const Params& p, float* sm, int b, int it) {
    float* h_s = sm;   // 512
    int tid = threadIdx.x;
    for (int k = tid; k < 512; k += 256) h_s[k] = p.xbuf[b * 1536 + k];   // h(it)
    __syncthreads();
    float* ao = p.a_out + (size_t)(it & 1) * (BB * 512) + b * 512;
    for (int j = tid; j < 512; j += 256) {
        const float* wr = p.Wh_w + (size_t)j * 512;
        float a0 = 0.f;
        #pragma unroll 4
        for (int k = 0; k < 512; k += 4) {
            float4 w = *(const float4*)(wr + k);
            float4 x = *(const float4*)(h_s + k);
            a0 += w.x*x.x + w.y*x.y + w.z*x.z + w.w*x.w;
        }
        ao[j] = a0 + p.Wh_b[j];
    }
}

// ----- cell item (bit-exact; s_t parity by it&1; Wh NOT folded — it's in phB) ---
static __device__ __forceinline__ void ph_cell(const Params& p, float* sm, int b, int it) {
    float* h_s = sm;          // 512
    float* c_s = sm + 512;    // 512
    float* red = sm + 1024;   // 256
    int tid = threadIdx.x;
    int parent = (it == 0) ? 0 : p.p_t[b * LL + it - 1];
    for (int k = tid; k < 512; k += 256)
        p.xbuf[b * 1536 + 1024 + k] = p.hs[((size_t)b * LL + parent) * 512 + k];
    const float* __restrict__ gp = p.gpart + (size_t)b * (GSG * 2048);
    for (int jj = tid; jj < 512; jj += 256) {
        float ig = gp[jj];
        float fg = gp[512 + jj];
        float gg = gp[1024 + jj];
        float og = gp[1536 + jj];
        #pragma unroll
        for (int s = 1; s < GSG; ++s) {
            const float* gps = gp + s * 2048;
            ig += gps[jj]; fg += gps[512 + jj]; gg += gps[1024 + jj]; og += gps[1536 + jj];
        }
        float si = 1.0f / (1.0f + expf(-ig));
        float sf = 1.0f / (1.0f + expf(-fg));
        float so = 1.0f / (1.0f + expf(-og));
        float cn = sf * p.c[b * 512 + jj] + si * tanhf(gg);
        float hn = so * tanhf(cn);
        c_s[jj] = cn; h_s[jj] = hn;
        p.c[b * 512 + jj] = cn;
    }
    __syncthreads();
    int nn = p.n_t[b * LL + it], tn = p.t_t[b * LL + it];
    for (int k = tid; k < 512; k += 256) {
        float hv = h_s[k], cv = c_s[k];
        p.hs[((size_t)b * LL + it) * 512 + k] = hv;
        p.xbuf[b * 1536 + k] = hv;
        p.xbuf[b * 1536 + 512 + k] = cv;
        p.xg[b * 1280 + 768 + k] = hv;
        p.xg[b * 1280 + 256 + k] = p.embT[(size_t)tn * 512 + k];
    }
    p.xg[b * 1280 + tid] = p.embN[(size_t)nn * 256 + tid];
    // s_t
    float acc = 0.0f;
    for (int k = tid; k < 512; k += 256) acc += h_s[k] * p.Ws_w[k];
    for (int k = tid; k < 512; k += 256) acc += c_s[k] * p.Ws_w[512 + k];
    red[tid] = acc;
    __syncthreads();
    for (int s2 = 128; s2 > 0; s2 >>= 1) {
        if (tid < s2) red[tid] += red[tid + s2];
        __syncthreads();
    }
    if (tid == 0)
        p.s_t[(it & 1) * BB + b] = 1.0f / (1.0f + expf(-(red[0] + p.Ws_b[0])));
}

// ------- scorefinal for step itm (a_out/s_t parity itm&1; lpart parity arg) -----
static __device__ __forceinline__ void ph_score(const Params& p, float* sm, int b, int itm, int par) {
    float* a_s  = sm;                 // 512
    float* vw_s = sm + 512;           // 512
    float* sc   = sm + 1024;          // 52 (pad 64)
    float* mv   = sm + 1088;          // 256
    int*   mi   = (int*)(sm + 1344);  // 256
    float* sv   = sm + 1600;          // 256
    float* sh   = sm + 1856;          // 2: vt, ve
    int tid = threadIdx.x;
    int lane = tid & 63, wv = tid >> 6;
    const float* ao = p.a_out + (size_t)(itm & 1) * (BB * 512) + b * 512;
    for (int k = tid; k < 512; k += 256) {
        a_s[k]  = ao[k];
        vw_s[k] = p.v_w[k];
    }
    __syncthreads();
    float vb0 = p.v_b[0];
    for (int w = wv; w < ATTN; w += 4) {
        int idx = itm + w - ATTN;
        int idxc = idx < 0 ? 0 : idx;
        bool mask = (idx < 0) || (p.n_t[b * LL + idxc] == EOF_N);
        const float* mrow = p.hs + ((size_t)b * LL + idxc) * 512;
        float acc = 0.0f;
        #pragma unroll
        for (int kk = 0; kk < 8; ++kk) {
            int k = lane + kk * 64;
            float x = a_s[k] + mrow[k];
            float e = __expf(2.0f * x);
            acc += vw_s[k] * (1.0f - 2.0f / (e + 1.0f));
        }
        for (int o = 32; o > 0; o >>= 1) acc += __shfl_down(acc, o);
        if (lane == 0) sc[w] = mask ? -1e20f : (acc + vb0);
    }
    __syncthreads();
    if (tid == 0) {
        float m = -INFINITY;
        for (int w = 0; w < ATTN; w++) m = fmaxf(m, sc[w]);
        float Z = 0.0f, emax = 0.0f;
        for (int w = 0; w < ATTN; w++) {
            float e = __expf(sc[w] - m);
            Z += e;
            if (e > emax) emax = e;
        }
        sc[50] = emax / Z;
        sc[51] = 1.0f;
    }
    int t_col = p.t_t[b * LL + itm];
    float lmax = -INFINITY; int limax = 0; float lsum = 0.0f;
    float vvr[NJIT];
    const float* __restrict__ lpb = p.lpart + (size_t)par * LPN + (size_t)b * (JBL * GSL * 256) + tid;
    #pragma unroll
    for (int i = 0; i < NJIT; ++i) {
        const float* base = lpb + i * (GSL * 256);
        float v = base[0];
        v += base[256];
        v += base[512];
        v += base[768];
        v += base[1024];
        v += base[1280];
        int j = i * 256 + tid;
        if (j < V_OUT) {
            vvr[i] = v;
            lsum += v;
            if (v > lmax) { lmax = v; limax = j; }
            if (j == t_col) sh[0] = v;
            if (j == EOF_T) sh[1] = v;
        }
    }
    mv[tid] = lmax; mi[tid] = limax; sv[tid] = lsum;
    __syncthreads();
    for (int s2 = 128; s2 > 0; s2 >>= 1) {
        if (tid < s2) {
            if (mv[tid + s2] > mv[tid] || (mv[tid + s2] == mv[tid] && mi[tid + s2] < mi[tid])) {
                mv[tid] = mv[tid + s2]; mi[tid] = mi[tid + s2];
            }
            sv[tid] += sv[tid + s2];
        }
        __syncthreads();
    }
    float M = mv[0]; int argJ = mi[0]; float sumL = sv[0];
    __syncthreads();
    float esum = 0.0f;
    #pragma unroll
    for (int i = 0; i < NJIT; ++i) {
        int j = i * 256 + tid;
        if (j < V_OUT) esum += expf(vvr[i] - M);
    }
    sv[tid] = esum;
    __syncthreads();
    for (int s2 = 128; s2 > 0; s2 >>= 1) {
        if (tid < s2) sv[tid] += sv[tid + s2];
        __syncthreads();
    }
    if (tid == 0) {
        float lse = logf(sv[0]);
        float st = p.s_t[(itm & 1) * BB + b];
        float amax = sc[50], asum = sc[51];
        float max_out = st * (-lse);
        float max_loc = (1.0f - st) * amax;
        bool cond = max_out > max_loc;
        const float CONST_T = CONF * logf(CONF) + 0.1f * logf(SM_VAL);
        float tl; int topi;
        if (!cond) {
            topi = argJ;
            float off = M + lse;
            float out_t = st * (sh[0] - off);
            float out_e = st * (sh[1] - off);
            float S = st * (sumL - (float)V_OUT * off);
            tl = CONST_T - (SM_VAL * (S - out_e - out_t) + CONF * out_t);
        } else {
            topi = 0;
            float S = (1.0f - st) * asum;
            tl = CONST_T - SM_VAL * S;
        }
        if (t_col == EOF_T) tl = 0.0f;
        p.tl_partial[itm * BB + b] = tl;
        p.out[1 + b * LL + itm] = (float)topi;
    }
}

// ---------------- kernels --------------------------------------------------------
// pre: gates(0), 2 items/block (128 blocks)
__global__ __launch_bounds__(256) void k_pre(Params p) {
    __shared__ __align__(16) float sm[3072];
    int g = blockIdx.x;
    int g1 = 2 * g, g2 = 2 * g + 1;
    ph_gates(p, sm, g1 & 31, g1 >> 5);
    ph_gates(p, sm, g2 & 31, g2 >> 5);
}

// phase A: cell(it) ONLY — the serial hop (32 blocks)
__global__ __launch_bounds__(256) void k_phA(Params p, int it) {
    __shared__ __align__(16) float sm[1280];
    ph_cell(p, sm, blockIdx.x, it);
}

// phase B: logits(it)[0,240) ‖ gates(it+1) pairs [240,368) ‖ score(it-1) [368,400)
//          ‖ Wh(it) [400,432).   lpart parity: logits par_l, score par_s.
__global__ __launch_bounds__(256) void k_phB(Params p, int it, int wg, int wsc,
                                             int par_l, int par_s) {
    __shared__ __align__(16) float sm[9216];
    int bx = blockIdx.x;
    if (bx < NLOG) {
        ph_logits(p, sm, bx, par_l);
    } else if (bx < NLOG + 128) {
        if (wg) {
            int g = bx - NLOG;
            int g1 = 2 * g, g2 = 2 * g + 1;
            ph_gates(p, sm, g1 & 31, g1 >> 5);
            ph_gates(p, sm, g2 & 31, g2 >> 5);
        }
    } else if (bx < NLOG + 160) {
        if (wsc) ph_score(p, sm, bx - (NLOG + 128), it - 1, par_s);
    } else {
        ph_wh(p, sm, bx - (NLOG + 160), it);
    }
}

// small-ws fallback: score as its own per-step kernel (single lpart parity)
__global__ __launch_bounds__(256) void k_phC(Params p, int it) {
    __shared__ __align__(16) float sm[1920];
    ph_score(p, sm, blockIdx.x, it, 0);
}

// final score(127) (big path)
__global__ __launch_bounds__(256) void k_final(Params p, int par) {
    __shared__ __align__(16) float sm[1920];
    ph_score(p, sm, blockIdx.x, LL - 1, par);
}

__global__ void k_sumloss(Params p) {
    __shared__ float r[256];
    float a = 0.0f;
    for (int i = threadIdx.x; i < BB * LL; i += 256) a += p.tl_partial[i];
    r[threadIdx.x] = a;
    __syncthreads();
    for (int s = 128; s > 0; s >>= 1) {
        if (threadIdx.x < s) r[threadIdx.x] += r[threadIdx.x + s];
        __syncthreads();
    }
    if (threadIdx.x == 0) p.out[0] = r[0];
}

extern "C" void kernel_launch(void* const* d_in, const int* in_sizes, int n_in,
                              void* d_out, int out_size, void* d_ws, size_t ws_size,
                              hipStream_t stream) {
    (void)in_sizes; (void)n_in; (void)out_size;
    Params p;
    p.n_t  = (const int*)d_in[0];
    p.t_t  = (const int*)d_in[1];
    p.p_t  = (const int*)d_in[2];
    p.embN = (const float*)d_in[3];
    p.embT = (const float*)d_in[4];
    p.w_ih = (const float*)d_in[5];
    p.w_hh = (const float*)d_in[6];
    p.b_ih = (const float*)d_in[7];
    p.b_hh = (const float*)d_in[8];
    p.Wh_w = (const float*)d_in[9];
    p.Wh_b = (const float*)d_in[10];
    p.v_w  = (const float*)d_in[11];
    p.v_b  = (const float*)d_in[12];
    p.Wg_w = (const float*)d_in[13];
    p.Wg_b = (const float*)d_in[14];
    p.Ws_w = (const float*)d_in[15];
    p.Ws_b = (const float*)d_in[16];
    p.out  = (float*)d_out;

    // workspace layout (floats)
    float* ws = (float*)d_ws;
    p.hs         = ws;                       // 2,097,152
    p.c          = p.hs + 2097152;           // 16,384
    p.xbuf       = p.c + 16384;              // 49,152  [h|c|hcp]
    p.xg         = p.xbuf + 49152;           // 40,960  [embN|embT|h]
    p.a_out      = p.xg + 40960;             // 32,768  (parity)
    p.s_t        = p.a_out + 32768;          // 64      (parity)
    p.tl_partial = p.s_t + 64;               // 4,096
    p.gpart      = p.tl_partial + 4096;      // 524,288  [b][s][j]
    p.lpart      = p.gpart + 524288;         // 2*LPN (big) / LPN (small)
    const size_t base_f = 2097152 + 16384 + 49152 + 40960 + 32768 + 64 + 4096 + 524288;
    const size_t req_big = (base_f + 2 * (size_t)LPN) * 4;
    bool big = (ws_size >= req_big);   // R8 measured: big path fits on this harness

    k_init<<<2048, 256, 0, stream>>>(p);
    k_pre<<<128, 256, 0, stream>>>(p);                        // gates(0)
    if (big) {
        for (int it = 0; it < LL; ++it) {
            k_phA<<<32, 256, 0, stream>>>(p, it);             // cell(it) — serial hop
            int wg  = (it < LL - 1) ? 1 : 0;
            int wsc = (it > 0) ? 1 : 0;
            k_phB<<<432, 256, 0, stream>>>(p, it, wg, wsc, it & 1, (it - 1) & 1);
        }
        k_final<<<32, 256, 0, stream>>>(p, (LL - 1) & 1);     // score(127), parity 1
    } else {
        for (int it = 0; it < LL; ++it) {
            k_phA<<<32, 256, 0, stream>>>(p, it);
            int wg = (it < LL - 1) ? 1 : 0;
            k_phB<<<432, 256, 0, stream>>>(p, it, wg, 0, 0, 0);   // no score in phB
            k_phC<<<32, 256, 0, stream>>>(p, it);                 // score(it), parity 0
        }
    }
    k_sumloss<<<1, 256, 0, stream>>>(p);
}